// Round 1
// baseline (202.989 us; speedup 1.0000x reference)
//
#include <hip/hip_runtime.h>

#define NN 512

typedef __attribute__((ext_vector_type(8))) short bf16x8;
typedef __attribute__((ext_vector_type(4))) float f32x4;

__device__ __forceinline__ unsigned short f2bf(float x) {
    union { float f; unsigned u; } c; c.f = x;
    unsigned u = c.u + 0x7fffu + ((c.u >> 16) & 1u);
    return (unsigned short)(u >> 16);
}

__device__ __forceinline__ int find_bin(float d) {
    int bin = 22;  // 22 = "no bin" (zero row in WdT/WscT)
    #pragma unroll
    for (int k = 0; k < 22; ++k) {
        float lo = (float)(1e-3 + k * ((20.0 - 1e-3) / 21.0));
        float hi = (k < 21) ? (float)(1e-3 + (k + 1) * ((20.0 - 1e-3) / 21.0)) : 1e8f;
        if (d > lo && d < hi) bin = k;
    }
    return bin;
}

// ---- p_i = s @ W_sp^T + b_sp : [B*N, 64] ----
__global__ __launch_bounds__(64) void k_node(const float* __restrict__ s,
        const float* __restrict__ Wsp, const float* __restrict__ bsp,
        float* __restrict__ p_i)
{
    __shared__ float srow[256];
    const int row = blockIdx.x, tid = threadIdx.x;
    *(float4*)&srow[tid * 4] = *(const float4*)&s[row * 256 + tid * 4];
    __syncthreads();
    const float* w = Wsp + tid * 256;
    float acc = bsp[tid];
    #pragma unroll 8
    for (int k = 0; k < 256; k += 4)
        acc += srow[k] * w[k] + srow[k+1] * w[k+1] + srow[k+2] * w[k+2] + srow[k+3] * w[k+3];
    p_i[row * 64 + tid] = acc;
}

// ---- qL/qR: per-node contributions through W1 cols [0:64) and [64:128) ----
__global__ __launch_bounds__(128) void k_ql(const float* __restrict__ p_i,
        const float* __restrict__ W1, float* __restrict__ qL, float* __restrict__ qR)
{
    __shared__ float pr[64];
    const int row = blockIdx.x, tid = threadIdx.x;
    if (tid < 16) *(float4*)&pr[tid * 4] = *(const float4*)&p_i[row * 64 + tid * 4];
    __syncthreads();
    const float* w = W1 + tid * 236;
    float aL = 0.f, aR = 0.f;
    #pragma unroll
    for (int k = 0; k < 64; ++k) { aL += pr[k] * w[k]; aR += pr[k] * w[64 + k]; }
    qL[row * 128 + tid] = aL;
    qR[row * 128 + tid] = aR;
}

// ---- relT[d] = (pos_emb(d) @ W_rp^T + b_rp) @ W1[:,128:192]^T + b1 ----
__global__ __launch_bounds__(128) void k_rel(const float* __restrict__ Wrp,
        const float* __restrict__ brp, const float* __restrict__ W1,
        const float* __restrict__ b1, float* __restrict__ relT)
{
    __shared__ float e[64];
    __shared__ float rp[64];
    const int tid = threadIdx.x;
    const float d = (float)((int)blockIdx.x - 511);
    if (tid < 32) {
        float f = powf(2056.0f, (float)tid * (1.0f / 32.0f));
        float ang = d * 3.14159265358979323846f / f;
        e[tid] = sinf(ang);
        e[tid + 32] = cosf(ang);
    }
    __syncthreads();
    if (tid < 64) {
        const float* w = Wrp + tid * 64;
        float a = brp[tid];
        #pragma unroll
        for (int k = 0; k < 64; ++k) a += e[k] * w[k];
        rp[tid] = a;
    }
    __syncthreads();
    const float* w = W1 + tid * 236 + 128;
    float a = b1[tid];
    #pragma unroll
    for (int k = 0; k < 64; ++k) a += rp[k] * w[k];
    relT[blockIdx.x * 128 + tid] = a;
}

// ---- distogram column gathers (transposed), row 22 = zeros ----
__global__ __launch_bounds__(128) void k_cols(const float* __restrict__ W1,
        float* __restrict__ WdT, float* __restrict__ WscT)
{
    const int bin = blockIdx.x, c = threadIdx.x;
    WdT[bin * 128 + c]  = (bin < 22) ? W1[c * 236 + 192 + bin] : 0.0f;
    WscT[bin * 128 + c] = (bin < 22) ? W1[c * 236 + 214 + bin] : 0.0f;
}

// ---- pack W (128x128) into MFMA B-fragment order, bf16 ----
// entry idx = nt*256 + ks*64 + lane ; holds B[k = ks*32 + (lane>>4)*8 + e][n = nt*16 + (lane&15)]
// where B[k][n] = W[n][k]
__global__ __launch_bounds__(64) void k_pack(const float* __restrict__ W,
        unsigned short* __restrict__ dst)
{
    const int idx = blockIdx.x * 64 + threadIdx.x;   // 0..2047
    const int lane = idx & 63, ks = (idx >> 6) & 3, nt = idx >> 8;
    const int n = nt * 16 + (lane & 15);
    const int kb = ks * 32 + (lane >> 4) * 8;
    const float* wp = W + n * 128 + kb;
    unsigned r0 = (unsigned)f2bf(wp[0]) | ((unsigned)f2bf(wp[1]) << 16);
    unsigned r1 = (unsigned)f2bf(wp[2]) | ((unsigned)f2bf(wp[3]) << 16);
    unsigned r2 = (unsigned)f2bf(wp[4]) | ((unsigned)f2bf(wp[5]) << 16);
    unsigned r3 = (unsigned)f2bf(wp[6]) | ((unsigned)f2bf(wp[7]) << 16);
    uint4 v = { r0, r1, r2, r3 };
    *(uint4*)(dst + idx * 8) = v;
}

// ---- main fused kernel: 1 block = (b,i) x 128 consecutive j ----
__global__ __launch_bounds__(512) void k_main(
    const float* __restrict__ t, const float* __restrict__ sct,
    const float* __restrict__ pmask,
    const float* __restrict__ qL, const float* __restrict__ qR,
    const float* __restrict__ relT, const float* __restrict__ WdT,
    const float* __restrict__ WscT,
    const unsigned short* __restrict__ w2f, const unsigned short* __restrict__ w3f,
    const float* __restrict__ b2, const float* __restrict__ b3,
    const float* __restrict__ lng, const float* __restrict__ lnb,
    float* __restrict__ out)
{
    __shared__ char h1[128 * 256];     // [128 rows][128 ch] bf16, XOR-swizzled; reused for h2
    __shared__ float qLs[128];
    __shared__ float b2s[128], b3s[128], gs[128], bs[128];
    __shared__ int   binD[128], binSC[128];
    __shared__ float maskv[128];

    const int tid  = threadIdx.x;
    const int blk  = blockIdx.x;
    const int bi   = blk >> 2;           // b*512 + i
    const int i    = bi & (NN - 1);
    const int bbase = bi & ~(NN - 1);    // b*512
    const int j0   = (blk & 3) * 128;

    // ---- stage small tables / bins ----
    if (tid < 32) {
        *(float4*)&qLs[tid * 4] = *(const float4*)&qL[bi * 128 + tid * 4];
    } else if (tid < 160) {
        int c = tid - 32; b2s[c] = b2[c]; b3s[c] = b3[c];
    } else if (tid < 288) {
        int c = tid - 160; gs[c] = lng[c]; bs[c] = lnb[c];
    } else if (tid < 416) {
        int jl = tid - 288; int j = j0 + jl;
        float ax = t[bi*3+0] - t[(bbase+j)*3+0];
        float ay = t[bi*3+1] - t[(bbase+j)*3+1];
        float az = t[bi*3+2] - t[(bbase+j)*3+2];
        binD[jl] = find_bin(sqrtf(ax*ax + ay*ay + az*az));
        float sx = sct[bi*3+0] - sct[(bbase+j)*3+0];
        float sy = sct[bi*3+1] - sct[(bbase+j)*3+1];
        float sz = sct[bi*3+2] - sct[(bbase+j)*3+2];
        binSC[jl] = find_bin(sqrtf(sx*sx + sy*sy + sz*sz));
        maskv[jl] = pmask[(size_t)bi * NN + j];
    }
    __syncthreads();

    // ---- build h1 = relu(qL + qR + relT + WdT[bin] + WscT[bin]) -> LDS bf16 ----
    {
        const int jl = tid >> 2, q = tid & 3;
        const int j  = j0 + jl;
        const float* qRp = qR + (bbase + j) * 128;
        const float* rTp = relT + (i - j + NN - 1) * 128;
        const float* dTp = WdT + binD[jl] * 128;
        const float* sTp = WscT + binSC[jl] * 128;
        const int swz = (jl & 15) << 4;
        #pragma unroll
        for (int u = 0; u < 8; ++u) {
            const int c = u * 16 + q * 4;
            float4 v0 = *(const float4*)(qLs + c);
            float4 v1 = *(const float4*)(qRp + c);
            float4 v2 = *(const float4*)(rTp + c);
            float4 v3 = *(const float4*)(dTp + c);
            float4 v4 = *(const float4*)(sTp + c);
            float x0 = fmaxf(v0.x + v1.x + v2.x + v3.x + v4.x, 0.0f);
            float x1 = fmaxf(v0.y + v1.y + v2.y + v3.y + v4.y, 0.0f);
            float x2 = fmaxf(v0.z + v1.z + v2.z + v3.z + v4.z, 0.0f);
            float x3 = fmaxf(v0.w + v1.w + v2.w + v3.w + v4.w, 0.0f);
            uint2 pk;
            pk.x = (unsigned)f2bf(x0) | ((unsigned)f2bf(x1) << 16);
            pk.y = (unsigned)f2bf(x2) | ((unsigned)f2bf(x3) << 16);
            *(uint2*)(h1 + ((jl * 256 + c * 2) ^ swz)) = pk;
        }
    }
    __syncthreads();

    const int l  = tid & 63;
    const int w  = tid >> 6;       // wave 0..7 owns local rows 16w..16w+15
    const int m  = l & 15;
    const int gq = l >> 4;

    // ---- GEMM2: h2 = relu(h1 @ W2^T + b2), written in place (wave-local rows) ----
    bf16x8 a[4];
    {
        const int row = w * 16 + m;
        const int rswz = (row & 15) << 4;
        const int base = row * 256 + gq * 16;
        #pragma unroll
        for (int ks = 0; ks < 4; ++ks)
            a[ks] = *(bf16x8*)(h1 + ((base + ks * 64) ^ rswz));
    }
    f32x4 acc[8];
    #pragma unroll
    for (int nt = 0; nt < 8; ++nt) {
        f32x4 c4 = { 0.f, 0.f, 0.f, 0.f };
        #pragma unroll
        for (int ks = 0; ks < 4; ++ks) {
            bf16x8 bf = *(const bf16x8*)(w2f + (nt * 256 + ks * 64 + l) * 8);
            c4 = __builtin_amdgcn_mfma_f32_16x16x32_bf16(a[ks], bf, c4, 0, 0, 0);
        }
        acc[nt] = c4;
    }
    #pragma unroll
    for (int nt = 0; nt < 8; ++nt) {
        const int c = nt * 16 + m;
        const float bb = b2s[c];
        #pragma unroll
        for (int r = 0; r < 4; ++r) {
            const int row = w * 16 + gq * 4 + r;
            unsigned short hv = f2bf(fmaxf(acc[nt][r] + bb, 0.0f));
            *(unsigned short*)(h1 + ((row * 256 + c * 2) ^ ((row & 15) << 4))) = hv;
        }
    }

    // ---- GEMM3: h3 = h2 @ W3^T + b3 ----
    bf16x8 a2[4];
    {
        const int row = w * 16 + m;
        const int rswz = (row & 15) << 4;
        const int base = row * 256 + gq * 16;
        #pragma unroll
        for (int ks = 0; ks < 4; ++ks)
            a2[ks] = *(bf16x8*)(h1 + ((base + ks * 64) ^ rswz));
    }
    f32x4 acc3[8];
    #pragma unroll
    for (int nt = 0; nt < 8; ++nt) {
        f32x4 c4 = { 0.f, 0.f, 0.f, 0.f };
        #pragma unroll
        for (int ks = 0; ks < 4; ++ks) {
            bf16x8 bf = *(const bf16x8*)(w3f + (nt * 256 + ks * 64 + l) * 8);
            c4 = __builtin_amdgcn_mfma_f32_16x16x32_bf16(a2[ks], bf, c4, 0, 0, 0);
        }
        acc3[nt] = c4;
    }

    // ---- + b3, LayerNorm over 128 ch, gamma/beta, mask, store ----
    #pragma unroll
    for (int nt = 0; nt < 8; ++nt) {
        const float bb = b3s[nt * 16 + m];
        #pragma unroll
        for (int r = 0; r < 4; ++r) acc3[nt][r] += bb;
    }
    float mu[4], rs[4];
    #pragma unroll
    for (int r = 0; r < 4; ++r) {
        float s1 = 0.f, s2 = 0.f;
        #pragma unroll
        for (int nt = 0; nt < 8; ++nt) { float v = acc3[nt][r]; s1 += v; s2 += v * v; }
        #pragma unroll
        for (int mm = 1; mm < 16; mm <<= 1) {
            s1 += __shfl_xor(s1, mm, 64);
            s2 += __shfl_xor(s2, mm, 64);
        }
        float mean = s1 * (1.0f / 128.0f);
        float var  = s2 * (1.0f / 128.0f) - mean * mean;
        mu[r] = mean;
        rs[r] = rsqrtf(var + 1e-5f);
    }
    const size_t base = ((size_t)bi * NN + j0) * 128;
    #pragma unroll
    for (int nt = 0; nt < 8; ++nt) {
        const int c = nt * 16 + m;
        const float gg = gs[c], bb = bs[c];
        #pragma unroll
        for (int r = 0; r < 4; ++r) {
            const int rl = w * 16 + gq * 4 + r;
            float y = (acc3[nt][r] - mu[r]) * rs[r] * gg + bb;
            out[base + (size_t)rl * 128 + c] = y * maskv[rl];
        }
    }
}

extern "C" void kernel_launch(void* const* d_in, const int* in_sizes, int n_in,
                              void* d_out, int out_size, void* d_ws, size_t ws_size,
                              hipStream_t stream)
{
    const float* s   = (const float*)d_in[0];
    const float* t   = (const float*)d_in[1];
    const float* sct = (const float*)d_in[2];
    const float* pm  = (const float*)d_in[3];
    const float* Wsp = (const float*)d_in[4];
    const float* bsp = (const float*)d_in[5];
    const float* Wrp = (const float*)d_in[6];
    const float* brp = (const float*)d_in[7];
    const float* W1  = (const float*)d_in[8];
    const float* b1  = (const float*)d_in[9];
    const float* W2  = (const float*)d_in[10];
    const float* b2  = (const float*)d_in[11];
    const float* W3  = (const float*)d_in[12];
    const float* b3  = (const float*)d_in[13];
    const float* lng = (const float*)d_in[14];
    const float* lnb = (const float*)d_in[15];

    float* ws   = (float*)d_ws;
    float* p_i  = ws;                 // 65536
    float* qL   = ws + 65536;         // 131072
    float* qR   = ws + 196608;        // 131072
    float* relT = ws + 327680;        // 130944
    float* WdT  = ws + 458624;        // 23*128
    float* WscT = ws + 461568;        // 23*128
    unsigned short* w2f = (unsigned short*)(ws + 464512);  // 2048*8 shorts
    unsigned short* w3f = (unsigned short*)(ws + 472704);

    k_cols<<<23, 128, 0, stream>>>(W1, WdT, WscT);
    k_node<<<1024, 64, 0, stream>>>(s, Wsp, bsp, p_i);
    k_rel<<<1023, 128, 0, stream>>>(Wrp, brp, W1, b1, relT);
    k_pack<<<32, 64, 0, stream>>>(W2, w2f);
    k_pack<<<32, 64, 0, stream>>>(W3, w3f);
    k_ql<<<1024, 128, 0, stream>>>(p_i, W1, qL, qR);
    k_main<<<4096, 512, 0, stream>>>(t, sct, pm, qL, qR, relT, WdT, WscT,
                                     w2f, w3f, b2, b3, lng, lnb, (float*)d_out);
}